// Round 1
// baseline (340.023 us; speedup 1.0000x reference)
//
#include <hip/hip_runtime.h>

typedef __bf16 bf16x8 __attribute__((ext_vector_type(8)));
typedef float floatx4 __attribute__((ext_vector_type(4)));

#define SCALE 0.125f
#define EPSF 1e-6f

__device__ inline unsigned short f2bf(float f) {
  union { float f; unsigned u; } x; x.f = f;
  unsigned r = x.u + 0x7FFFu + ((x.u >> 16) & 1u);
  return (unsigned short)(r >> 16);
}

__device__ inline floatx4 mfma16(bf16x8 a, bf16x8 b, floatx4 c) {
  return __builtin_amdgcn_mfma_f32_16x16x32_bf16(a, b, c, 0, 0, 0);
}

// ---------- fp32 -> bf16 cast, 8 elems/thread (n divisible by 2048) ----------
__global__ __launch_bounds__(256) void cast_bf16_kernel(const float* __restrict__ in,
                                                        unsigned short* __restrict__ out,
                                                        int n) {
  int i = (blockIdx.x * 256 + threadIdx.x) * 8;
  if (i >= n) return;
  float4 v0 = *(const float4*)(in + i);
  float4 v1 = *(const float4*)(in + i + 4);
  __align__(16) unsigned short o[8] = {f2bf(v0.x), f2bf(v0.y), f2bf(v0.z), f2bf(v0.w),
                                       f2bf(v1.x), f2bf(v1.y), f2bf(v1.z), f2bf(v1.w)};
  *(float4*)(out + i) = *(float4*)o;
}

// ---------- bf16 GEMM: C[M,N] = A[M,K] * Bt[N,K]^T ; EP=0: bf16 out, EP=1: f32 out + bias ----------
// 128x128 C-tile, 4 waves, each wave 64x64 via 4x4 grid of 16x16x32 MFMAs, BK=32.
template <int EP>
__global__ __launch_bounds__(256, 2) void gemm_bt(const unsigned short* __restrict__ A,
                                                  const unsigned short* __restrict__ Bt,
                                                  void* __restrict__ Cout,
                                                  const float* __restrict__ bias,
                                                  int M, int N, int K) {
  __shared__ unsigned short sA[128 * 32];
  __shared__ unsigned short sB[128 * 32];
  const int m0 = blockIdx.y * 128, n0 = blockIdx.x * 128;
  const int tid = threadIdx.x;
  const int lane = tid & 63, wave = tid >> 6;
  const int qd = lane >> 4, l15 = lane & 15;
  const int wr = (wave >> 1) * 64, wc = (wave & 1) * 64;
  const int srow = tid >> 2, scol = (tid & 3) * 8;
  const unsigned short* Ag = A + (long)(m0 + srow) * K + scol;
  const unsigned short* Bg = Bt + (long)(n0 + srow) * K + scol;
  floatx4 acc[4][4] = {};
  for (int k0 = 0; k0 < K; k0 += 32) {
    float4 a0 = *(const float4*)(Ag + k0);
    float4 a1 = *(const float4*)(Ag + (long)64 * K + k0);
    float4 b0 = *(const float4*)(Bg + k0);
    float4 b1 = *(const float4*)(Bg + (long)64 * K + k0);
    __syncthreads();
    *(float4*)&sA[srow * 32 + scol] = a0;
    *(float4*)&sA[(srow + 64) * 32 + scol] = a1;
    *(float4*)&sB[srow * 32 + scol] = b0;
    *(float4*)&sB[(srow + 64) * 32 + scol] = b1;
    __syncthreads();
    bf16x8 af[4], bf[4];
#pragma unroll
    for (int i = 0; i < 4; i++) af[i] = *(const bf16x8*)&sA[(wr + i * 16 + l15) * 32 + qd * 8];
#pragma unroll
    for (int j = 0; j < 4; j++) bf[j] = *(const bf16x8*)&sB[(wc + j * 16 + l15) * 32 + qd * 8];
#pragma unroll
    for (int i = 0; i < 4; i++)
#pragma unroll
      for (int j = 0; j < 4; j++) acc[i][j] = mfma16(af[i], bf[j], acc[i][j]);
  }
#pragma unroll
  for (int i = 0; i < 4; i++) {
#pragma unroll
    for (int j = 0; j < 4; j++) {
      const int col = n0 + wc + j * 16 + l15;
#pragma unroll
      for (int r = 0; r < 4; r++) {
        const int row = m0 + wr + i * 16 + qd * 4 + r;  // C/D: col=lane&15, row=quad*4+reg (m89/m91)
        if (EP == 0) {
          ((unsigned short*)Cout)[(long)row * N + col] = f2bf(acc[i][j][r]);
        } else {
          ((float*)Cout)[(long)row * N + col] = acc[i][j][r] + bias[col];
        }
      }
    }
  }
}

// ---------- V transpose: qkv[b][n][2][h][d] -> vT[(b*12+h)][d][n] ----------
__global__ __launch_bounds__(256) void transpose_v(const unsigned short* __restrict__ qkv,
                                                   unsigned short* __restrict__ vT) {
  __shared__ unsigned short tile[64][72];
  const int bh = blockIdx.y;  // 0..95
  const int b = bh / 12, h = bh % 12;
  const int n0 = blockIdx.x * 64;
  const int t = threadIdx.x;
  {
    const int nr = t >> 2, dc = (t & 3) * 16;
    const unsigned short* src = qkv + (long)(b * 1024 + n0 + nr) * 2304 + 2 * 768 + h * 64 + dc;
    float4 v0 = *(const float4*)src;
    float4 v1 = *(const float4*)(src + 8);
    *(float4*)&tile[nr][dc] = v0;
    *(float4*)&tile[nr][dc + 8] = v1;
  }
  __syncthreads();
  {
    const int d = t >> 2, nc = (t & 3) * 16;
    __align__(16) unsigned short o[16];
#pragma unroll
    for (int jj = 0; jj < 16; jj++) o[jj] = tile[nc + jj][d];
    unsigned short* dst = vT + (long)(bh * 64 + d) * 1024 + n0 + nc;
    *(float4*)dst = *(float4*)&o[0];
    *(float4*)(dst + 8) = *(float4*)&o[8];
  }
}

// ---------- attention: per block = one (b,h,64-q-rows); wave = 16 q rows ----------
// No max-subtraction (logits ~N(0,1), exp is fp32-safe); policy weight: w=policy[col], 1 on diag.
__global__ __launch_bounds__(256, 2) void attn_kernel(const unsigned short* __restrict__ qkv,
                                                      const unsigned short* __restrict__ vT,
                                                      const float* __restrict__ policy,
                                                      unsigned short* __restrict__ aout) {
  __shared__ unsigned short sP[4][16 * 32];
  const int qt = blockIdx.x & 15, bh = blockIdx.x >> 4;
  const int b = bh / 12, h = bh % 12;
  const int wave = threadIdx.x >> 6, lane = threadIdx.x & 63;
  const int qd = lane >> 4, l15 = lane & 15;
  const int q0 = qt * 64 + wave * 16;
  // Q fragments (A-layout: m=lane&15, k=quad*8+j), resident for whole kernel
  const unsigned short* qbase = qkv + (long)(b * 1024 + q0 + l15) * 2304 + h * 64 + qd * 8;
  bf16x8 qf0 = *(const bf16x8*)qbase;
  bf16x8 qf1 = *(const bf16x8*)(qbase + 32);
  const unsigned short* kbase = qkv + (long)(b * 1024 + l15) * 2304 + 768 + h * 64 + qd * 8;
  const unsigned short* vbase = vT + (long)bh * 64 * 1024 + qd * 8;
  const float* pbase = policy + b * 1024;
  floatx4 O[4] = {};
  float lac[4] = {0.f, 0.f, 0.f, 0.f};
  for (int c0 = 0; c0 < 1024; c0 += 32) {
    const unsigned short* kp = kbase + (long)c0 * 2304;
    bf16x8 k00 = *(const bf16x8*)kp;
    bf16x8 k01 = *(const bf16x8*)(kp + 32);
    bf16x8 k10 = *(const bf16x8*)(kp + (long)16 * 2304);
    bf16x8 k11 = *(const bf16x8*)(kp + (long)16 * 2304 + 32);
    floatx4 z = {0.f, 0.f, 0.f, 0.f};
    floatx4 s0 = mfma16(qf1, k01, mfma16(qf0, k00, z));
    floatx4 s1 = mfma16(qf1, k11, mfma16(qf0, k10, z));
    const float p0 = pbase[c0 + l15];
    const float p1 = pbase[c0 + 16 + l15];
#pragma unroll
    for (int r = 0; r < 4; r++) {
      const int grow = q0 + qd * 4 + r;
      float a0 = __expf(s0[r] * SCALE) * ((grow == c0 + l15) ? 1.0f : p0);
      float a1 = __expf(s1[r] * SCALE) * ((grow == c0 + 16 + l15) ? 1.0f : p1);
      lac[r] += a0 + a1;
      // C-layout -> LDS (row=quad*4+r, col=lane&15 per 16-tile)
      sP[wave][(qd * 4 + r) * 32 + l15] = f2bf(a0);
      sP[wave][(qd * 4 + r) * 32 + 16 + l15] = f2bf(a1);
    }
    __syncthreads();
    // re-read P in A-layout: m=lane&15, k=quad*8+j  (one 32-ctx K-step)
    bf16x8 pf = *(const bf16x8*)&sP[wave][l15 * 32 + qd * 8];
#pragma unroll
    for (int j = 0; j < 4; j++) {
      bf16x8 vf = *(const bf16x8*)(vbase + (long)(j * 16 + l15) * 1024 + c0);
      O[j] = mfma16(pf, vf, O[j]);
    }
    __syncthreads();
  }
  float linv[4];
#pragma unroll
  for (int r = 0; r < 4; r++) {
    float l = lac[r];
    l += __shfl_xor(l, 1, 64);
    l += __shfl_xor(l, 2, 64);
    l += __shfl_xor(l, 4, 64);
    l += __shfl_xor(l, 8, 64);
    linv[r] = 1.0f / (l + EPSF);
  }
  const long ob = (long)(b * 1024 + q0 + qd * 4) * 768 + h * 64;
#pragma unroll
  for (int j = 0; j < 4; j++)
#pragma unroll
    for (int r = 0; r < 4; r++) aout[ob + (long)r * 768 + j * 16 + l15] = f2bf(O[j][r] * linv[r]);
}

extern "C" void kernel_launch(void* const* d_in, const int* in_sizes, int n_in,
                              void* d_out, int out_size, void* d_ws, size_t ws_size,
                              hipStream_t stream) {
  const float* x      = (const float*)d_in[0];   // [8,1024,768]
  const float* policy = (const float*)d_in[1];   // [8,1024,1]
  const float* qkv_w  = (const float*)d_in[2];   // [2304,768]
  const float* proj_w = (const float*)d_in[3];   // [768,768]
  const float* proj_b = (const float*)d_in[4];   // [768]
  float* out = (float*)d_out;                    // [8,1024,768] fp32

  char* ws = (char*)d_ws;
  unsigned short* xb    = (unsigned short*)(ws + 0);         // 12,582,912 B
  unsigned short* wqkv  = (unsigned short*)(ws + 12582912);  //  3,538,944 B
  unsigned short* wproj = (unsigned short*)(ws + 16121856);  //  1,179,648 B
  unsigned short* qkvb  = (unsigned short*)(ws + 17301504);  // 37,748,736 B
  unsigned short* vT    = (unsigned short*)(ws + 55050240);  // 12,582,912 B
  unsigned short* aoutb = (unsigned short*)(ws + 67633152);  // 12,582,912 B  (end 80,216,064)

  cast_bf16_kernel<<<3072, 256, 0, stream>>>(x, xb, 6291456);
  cast_bf16_kernel<<<864, 256, 0, stream>>>(qkv_w, wqkv, 1769472);
  cast_bf16_kernel<<<288, 256, 0, stream>>>(proj_w, wproj, 589824);
  gemm_bt<0><<<dim3(18, 64), 256, 0, stream>>>(xb, wqkv, qkvb, nullptr, 8192, 2304, 768);
  transpose_v<<<dim3(16, 96), 256, 0, stream>>>(qkvb, vT);
  attn_kernel<<<dim3(1536), 256, 0, stream>>>(qkvb, vT, policy, aoutb);
  gemm_bt<1><<<dim3(6, 64), 256, 0, stream>>>(aoutb, wproj, out, proj_b, 8192, 768, 768);
}

// Round 2
// 254.974 us; speedup vs baseline: 1.3336x; 1.3336x over previous
//
#include <hip/hip_runtime.h>

typedef __bf16 bf16x8 __attribute__((ext_vector_type(8)));
typedef float floatx4 __attribute__((ext_vector_type(4)));

#define SCALE 0.125f
#define EPSF 1e-6f

__device__ inline unsigned short f2bf(float f) {
  union { float f; unsigned u; } x; x.f = f;
  unsigned r = x.u + 0x7FFFu + ((x.u >> 16) & 1u);
  return (unsigned short)(r >> 16);
}

__device__ inline floatx4 mfma16(bf16x8 a, bf16x8 b, floatx4 c) {
  return __builtin_amdgcn_mfma_f32_16x16x32_bf16(a, b, c, 0, 0, 0);
}

// async global->LDS, 16B per lane; LDS dest = wave-uniform base + lane*16 (m97 pattern)
__device__ inline void gll16(const unsigned short* g, unsigned short* l) {
  __builtin_amdgcn_global_load_lds((__attribute__((address_space(1))) void*)g,
                                   (__attribute__((address_space(3))) void*)l, 16, 0, 0);
}

// ---------- fp32 -> bf16 cast, 8 elems/thread ----------
__global__ __launch_bounds__(256) void cast_bf16_kernel(const float* __restrict__ in,
                                                        unsigned short* __restrict__ out,
                                                        int n) {
  int i = (blockIdx.x * 256 + threadIdx.x) * 8;
  if (i >= n) return;
  float4 v0 = *(const float4*)(in + i);
  float4 v1 = *(const float4*)(in + i + 4);
  __align__(16) unsigned short o[8] = {f2bf(v0.x), f2bf(v0.y), f2bf(v0.z), f2bf(v0.w),
                                       f2bf(v1.x), f2bf(v1.y), f2bf(v1.z), f2bf(v1.w)};
  *(float4*)(out + i) = *(float4*)o;
}

// ---------- bf16 GEMM: C[M,N] = A[M,K] * Bt[N,K]^T ; EP=0: bf16 out, EP=1: f32 out + bias ----------
// 128x128 C-tile, 4 waves, 4x4 grid of 16x16x32 MFMAs/wave, BK=32, global_load_lds staging (m97).
template <int EP>
__global__ __launch_bounds__(256, 2) void gemm_bt(const unsigned short* __restrict__ A,
                                                  const unsigned short* __restrict__ Bt,
                                                  void* __restrict__ Cout,
                                                  const float* __restrict__ bias,
                                                  int M, int N, int K) {
  __shared__ __align__(16) unsigned short sA[128 * 32];
  __shared__ __align__(16) unsigned short sB[128 * 32];
  const int m0 = blockIdx.y * 128, n0 = blockIdx.x * 128;
  const int tid = threadIdx.x;
  const int lane = tid & 63, wave = tid >> 6;
  const int qd = lane >> 4, l15 = lane & 15;
  const int wr = (wave >> 1) * 64, wc = (wave & 1) * 64;
  const int srow = tid >> 2, scol = (tid & 3) * 8;
  const unsigned short* Ag = A + (long)(m0 + srow) * K + scol;
  const unsigned short* Bg = Bt + (long)(n0 + srow) * K + scol;
  unsigned short* sAp = &sA[wave * 512];   // byte offset 16*tid within block
  unsigned short* sBp = &sB[wave * 512];
  floatx4 acc[4][4] = {};
  for (int k0 = 0; k0 < K; k0 += 32) {
    __syncthreads();
    gll16(Ag + k0, sAp);
    gll16(Ag + (long)64 * K + k0, sAp + 2048);
    gll16(Bg + k0, sBp);
    gll16(Bg + (long)64 * K + k0, sBp + 2048);
    __syncthreads();
    bf16x8 af[4], bf[4];
#pragma unroll
    for (int i = 0; i < 4; i++) af[i] = *(const bf16x8*)&sA[(wr + i * 16 + l15) * 32 + qd * 8];
#pragma unroll
    for (int j = 0; j < 4; j++) bf[j] = *(const bf16x8*)&sB[(wc + j * 16 + l15) * 32 + qd * 8];
#pragma unroll
    for (int i = 0; i < 4; i++)
#pragma unroll
      for (int j = 0; j < 4; j++) acc[i][j] = mfma16(af[i], bf[j], acc[i][j]);
  }
#pragma unroll
  for (int i = 0; i < 4; i++) {
#pragma unroll
    for (int j = 0; j < 4; j++) {
      const int col = n0 + wc + j * 16 + l15;
#pragma unroll
      for (int r = 0; r < 4; r++) {
        const int row = m0 + wr + i * 16 + qd * 4 + r;  // C/D: col=lane&15, row=quad*4+reg
        if (EP == 0) {
          ((unsigned short*)Cout)[(long)row * N + col] = f2bf(acc[i][j][r]);
        } else {
          ((float*)Cout)[(long)row * N + col] = acc[i][j][r] + bias[col];
        }
      }
    }
  }
}

// ---------- V transpose: qkv[b][n][2][h][d] -> vT[(b*12+h)][d][n] ----------
__global__ __launch_bounds__(256) void transpose_v(const unsigned short* __restrict__ qkv,
                                                   unsigned short* __restrict__ vT) {
  __shared__ unsigned short tile[64][72];
  const int bh = blockIdx.y;  // 0..95
  const int b = bh / 12, h = bh % 12;
  const int n0 = blockIdx.x * 64;
  const int t = threadIdx.x;
  {
    const int nr = t >> 2, dc = (t & 3) * 16;
    const unsigned short* src = qkv + (long)(b * 1024 + n0 + nr) * 2304 + 2 * 768 + h * 64 + dc;
    float4 v0 = *(const float4*)src;
    float4 v1 = *(const float4*)(src + 8);
    *(float4*)&tile[nr][dc] = v0;
    *(float4*)&tile[nr][dc + 8] = v1;
  }
  __syncthreads();
  {
    const int d = t >> 2, nc = (t & 3) * 16;
    __align__(16) unsigned short o[16];
#pragma unroll
    for (int jj = 0; jj < 16; jj++) o[jj] = tile[nc + jj][d];
    unsigned short* dst = vT + (long)(bh * 64 + d) * 1024 + n0 + nc;
    *(float4*)dst = *(float4*)&o[0];
    *(float4*)(dst + 8) = *(float4*)&o[8];
  }
}

// ---------- attention: block = (b,h,128 q-rows), wave = 32 q rows (2 MFMA tiles), NO barriers ----------
// sP is wave-private (lgkmcnt ordering only). Row stride 40 shorts: 16B-aligned rows + de-aliased banks.
__global__ __launch_bounds__(256, 4) void attn_kernel(const unsigned short* __restrict__ qkv,
                                                      const unsigned short* __restrict__ vT,
                                                      const float* __restrict__ policy,
                                                      unsigned short* __restrict__ aout) {
  __shared__ __align__(16) unsigned short sP[4][2][16 * 40];
  const int bid = blockIdx.x;
  const int bh = bid % 96, qt = bid / 96;  // bh-fast: all 8 blocks of a bh share an XCD slot (L2 locality)
  const int b = bh / 12, h = bh % 12;
  const int wave = threadIdx.x >> 6, lane = threadIdx.x & 63;
  const int qd = lane >> 4, l15 = lane & 15;
  const int q0 = qt * 128 + wave * 32;
  const unsigned short* qb = qkv + (long)(b * 1024 + q0 + l15) * 2304 + h * 64 + qd * 8;
  bf16x8 qf00 = *(const bf16x8*)qb;
  bf16x8 qf01 = *(const bf16x8*)(qb + 32);
  bf16x8 qf10 = *(const bf16x8*)(qb + (long)16 * 2304);
  bf16x8 qf11 = *(const bf16x8*)(qb + (long)16 * 2304 + 32);
  const unsigned short* kbase = qkv + (long)(b * 1024 + l15) * 2304 + 768 + h * 64 + qd * 8;
  const unsigned short* vbase = vT + (long)bh * 64 * 1024 + qd * 8;
  const float* pbase = policy + b * 1024;
  unsigned short* sp0 = &sP[wave][0][0];
  unsigned short* sp1 = &sP[wave][1][0];
  floatx4 O0[4] = {}, O1[4] = {};
  float lac0[4] = {0.f, 0.f, 0.f, 0.f}, lac1[4] = {0.f, 0.f, 0.f, 0.f};
  for (int c0 = 0; c0 < 1024; c0 += 32) {
    const unsigned short* kp = kbase + (long)c0 * 2304;
    bf16x8 k00 = *(const bf16x8*)kp;
    bf16x8 k01 = *(const bf16x8*)(kp + 32);
    bf16x8 k10 = *(const bf16x8*)(kp + (long)16 * 2304);
    bf16x8 k11 = *(const bf16x8*)(kp + (long)16 * 2304 + 32);
    floatx4 z = {0.f, 0.f, 0.f, 0.f};
    floatx4 s00 = mfma16(qf01, k01, mfma16(qf00, k00, z));
    floatx4 s01 = mfma16(qf01, k11, mfma16(qf00, k10, z));
    floatx4 s10 = mfma16(qf11, k01, mfma16(qf10, k00, z));
    floatx4 s11 = mfma16(qf11, k11, mfma16(qf10, k10, z));
    const float p0 = pbase[c0 + l15];
    const float p1 = pbase[c0 + 16 + l15];
#pragma unroll
    for (int r = 0; r < 4; r++) {
      const int row = qd * 4 + r;
      const int g0 = q0 + row, g1 = q0 + 16 + row;
      float a;
      a = __expf(s00[r] * SCALE) * ((g0 == c0 + l15) ? 1.0f : p0);
      lac0[r] += a; sp0[row * 40 + l15] = f2bf(a);
      a = __expf(s01[r] * SCALE) * ((g0 == c0 + 16 + l15) ? 1.0f : p1);
      lac0[r] += a; sp0[row * 40 + 16 + l15] = f2bf(a);
      a = __expf(s10[r] * SCALE) * ((g1 == c0 + l15) ? 1.0f : p0);
      lac1[r] += a; sp1[row * 40 + l15] = f2bf(a);
      a = __expf(s11[r] * SCALE) * ((g1 == c0 + 16 + l15) ? 1.0f : p1);
      lac1[r] += a; sp1[row * 40 + 16 + l15] = f2bf(a);
    }
    bf16x8 pf0 = *(const bf16x8*)&sp0[l15 * 40 + qd * 8];
    bf16x8 pf1 = *(const bf16x8*)&sp1[l15 * 40 + qd * 8];
#pragma unroll
    for (int j = 0; j < 4; j++) {
      bf16x8 vf = *(const bf16x8*)(vbase + (long)(j * 16 + l15) * 1024 + c0);
      O0[j] = mfma16(pf0, vf, O0[j]);
      O1[j] = mfma16(pf1, vf, O1[j]);
    }
  }
  float linv0[4], linv1[4];
#pragma unroll
  for (int r = 0; r < 4; r++) {
    float l0 = lac0[r], l1 = lac1[r];
    l0 += __shfl_xor(l0, 1); l0 += __shfl_xor(l0, 2);
    l0 += __shfl_xor(l0, 4); l0 += __shfl_xor(l0, 8);
    l1 += __shfl_xor(l1, 1); l1 += __shfl_xor(l1, 2);
    l1 += __shfl_xor(l1, 4); l1 += __shfl_xor(l1, 8);
    linv0[r] = 1.0f / (l0 + EPSF);
    linv1[r] = 1.0f / (l1 + EPSF);
  }
  const long ob = (long)(b * 1024 + q0 + qd * 4) * 768 + h * 64 + l15;
#pragma unroll
  for (int j = 0; j < 4; j++)
#pragma unroll
    for (int r = 0; r < 4; r++) {
      aout[ob + (long)r * 768 + j * 16] = f2bf(O0[j][r] * linv0[r]);
      aout[ob + (long)(16 * 768) + r * 768 + j * 16] = f2bf(O1[j][r] * linv1[r]);
    }
}

extern "C" void kernel_launch(void* const* d_in, const int* in_sizes, int n_in,
                              void* d_out, int out_size, void* d_ws, size_t ws_size,
                              hipStream_t stream) {
  const float* x      = (const float*)d_in[0];   // [8,1024,768]
  const float* policy = (const float*)d_in[1];   // [8,1024,1]
  const float* qkv_w  = (const float*)d_in[2];   // [2304,768]
  const float* proj_w = (const float*)d_in[3];   // [768,768]
  const float* proj_b = (const float*)d_in[4];   // [768]
  float* out = (float*)d_out;                    // [8,1024,768] fp32

  char* ws = (char*)d_ws;
  unsigned short* xb    = (unsigned short*)(ws + 0);         // 12,582,912 B
  unsigned short* wqkv  = (unsigned short*)(ws + 12582912);  //  3,538,944 B
  unsigned short* wproj = (unsigned short*)(ws + 16121856);  //  1,179,648 B
  unsigned short* qkvb  = (unsigned short*)(ws + 17301504);  // 37,748,736 B
  unsigned short* vT    = (unsigned short*)(ws + 55050240);  // 12,582,912 B
  unsigned short* aoutb = (unsigned short*)(ws + 67633152);  // 12,582,912 B  (end 80,216,064)

  cast_bf16_kernel<<<3072, 256, 0, stream>>>(x, xb, 6291456);
  cast_bf16_kernel<<<864, 256, 0, stream>>>(qkv_w, wqkv, 1769472);
  cast_bf16_kernel<<<288, 256, 0, stream>>>(proj_w, wproj, 589824);
  gemm_bt<0><<<dim3(18, 64), 256, 0, stream>>>(xb, wqkv, qkvb, nullptr, 8192, 2304, 768);
  transpose_v<<<dim3(16, 96), 256, 0, stream>>>(qkvb, vT);
  attn_kernel<<<dim3(768), 256, 0, stream>>>(qkvb, vT, policy, aoutb);
  gemm_bt<1><<<dim3(6, 64), 256, 0, stream>>>(aoutb, wproj, out, proj_b, 8192, 768, 768);
}